// Round 2
// baseline (1131.261 us; speedup 1.0000x reference)
//
#include <hip/hip_runtime.h>
#include <cstdint>

// LlamaSmoothquantMLP on MI355X (gfx950).
// NOTE: harness materializes ALL integer inputs as int32 on device
// ("integer -> const int*"), so int8 tensors arrive as int32. We pack them
// to true int8 in d_ws first, then run int8 MFMA GEMMs.
//
// Pass 0: pack int32->int8 for X, Wg, Wu, Wd into d_ws.
// Kernel 1: fused gate+up int8 GEMM + dequant + SiLU + mul + requant -> int8 Q
// Kernel 2: down int8 GEMM + dequant + bias -> fp32 out
//
// GEMMs: A [M,K] row-major, B [N,K] row-major (K-contiguous both sides).
// MFMA: v_mfma_i32_32x32x32_i8, block tile 128x128, BK=128, 4 waves @ 64x64.
// Staging: global_load_lds width=16 with XOR-8 chunk swizzle applied to the
// *global* source address (global_load_lds LDS mapping is wave-uniform
// base + lane*16, fixed), so ds_read_b128 fragment reads are conflict-free.

typedef int v4i  __attribute__((ext_vector_type(4)));
typedef int v16i __attribute__((ext_vector_type(16)));

typedef const void __attribute__((address_space(1)))* gas_ptr;
typedef void __attribute__((address_space(3)))* las_ptr;

static constexpr int M_TOT = 4096;   // B*S = 2*2048
static constexpr int HDIM  = 4096;   // hidden
static constexpr int IDIM  = 11008;  // intermediate

#define BM 128
#define BN 128
#define BK 128

// ---------------- pack int32 -> int8 ----------------
// Each thread: 16 elements (4x int4 load, 1x int4 store of packed bytes).
__global__ __launch_bounds__(256) void k_pack(const int* __restrict__ src,
                                              int8_t* __restrict__ dst, int n16) {
  int t = blockIdx.x * blockDim.x + threadIdx.x;
  if (t >= n16) return;
  const int4* s = (const int4*)(src) + t * 4;
  int4 v0 = s[0], v1 = s[1], v2 = s[2], v3 = s[3];
  int p0 = (v0.x & 0xff) | ((v0.y & 0xff) << 8) | ((v0.z & 0xff) << 16) | (v0.w << 24);
  int p1 = (v1.x & 0xff) | ((v1.y & 0xff) << 8) | ((v1.z & 0xff) << 16) | (v1.w << 24);
  int p2 = (v2.x & 0xff) | ((v2.y & 0xff) << 8) | ((v2.z & 0xff) << 16) | (v2.w << 24);
  int p3 = (v3.x & 0xff) | ((v3.y & 0xff) << 8) | ((v3.z & 0xff) << 16) | (v3.w << 24);
  ((int4*)dst)[t] = make_int4(p0, p1, p2, p3);
}

// ---------------- staging ----------------
// Stage one 128-row x 128-byte tile (16 KiB) global->LDS asynchronously.
// 256 threads x 4 iters x 16B. LDS slot s of row r holds global chunk s^(r&7).
__device__ __forceinline__ void async_stage_16kb(const int8_t* __restrict__ gbase,
                                                 int ld, int8_t* lds, int tid) {
#pragma unroll
  for (int it = 0; it < 4; ++it) {
    const int chunk = it * 256 + tid;      // 0..1023
    const int row   = chunk >> 3;          // 0..127
    const int slot  = chunk & 7;           // 0..7
    const int gch   = slot ^ (row & 7);    // swizzled source chunk
    const int8_t* g = gbase + row * ld + gch * 16;
    int8_t* l = lds + chunk * 16;
    __builtin_amdgcn_global_load_lds((gas_ptr)g, (las_ptr)l, 16, 0, 0);
  }
}

// Read a 16-byte A/B fragment for row `row`, K-chunk base `kc` (0,2,4,6),
// lane-half `half` (lane>>5). Undo the XOR-8 swizzle.
__device__ __forceinline__ v4i frag_ld(const int8_t* lds, int row, int kc, int half) {
  const int ch  = kc + half;
  const int sch = ch ^ (row & 7);
  return *(const v4i*)(lds + row * 128 + sch * 16);
}

#define MFMA_I8(a, b, c) __builtin_amdgcn_mfma_i32_32x32x32_i8((a), (b), (c), 0, 0, 0)

__global__ __launch_bounds__(256, 2) void k_gateup(
    const int8_t* __restrict__ X,
    const int8_t* __restrict__ Wg,
    const int8_t* __restrict__ Wu,
    const float* __restrict__ gate_a, const float* __restrict__ gate_b,
    const float* __restrict__ up_a,   const float* __restrict__ up_b,
    const float* __restrict__ down_scale,
    int8_t* __restrict__ Q) {
  __shared__ __align__(16) int8_t sA[BM * BK];
  __shared__ __align__(16) int8_t sG[BN * BK];
  __shared__ __align__(16) int8_t sU[BN * BK];

  const int tid  = threadIdx.x;
  const int lane = tid & 63;
  const int wave = tid >> 6;
  const int wm   = wave >> 1;
  const int wn   = wave & 1;
  const int half = lane >> 5;
  const int ln31 = lane & 31;

  const int m0 = blockIdx.x * BM;
  const int n0 = blockIdx.y * BN;

  const int8_t* Ab = X  + (size_t)m0 * HDIM;
  const int8_t* Gb = Wg + (size_t)n0 * HDIM;
  const int8_t* Ub = Wu + (size_t)n0 * HDIM;

  v16i accG[2][2], accU[2][2];
#pragma unroll
  for (int i = 0; i < 2; ++i)
#pragma unroll
    for (int j = 0; j < 2; ++j)
#pragma unroll
      for (int e = 0; e < 16; ++e) { accG[i][j][e] = 0; accU[i][j][e] = 0; }

  const int rA = wm * 64 + ln31;
  const int rB = wn * 64 + ln31;

  for (int k0 = 0; k0 < HDIM; k0 += BK) {
    async_stage_16kb(Ab + k0, HDIM, sA, tid);
    async_stage_16kb(Gb + k0, HDIM, sG, tid);
    async_stage_16kb(Ub + k0, HDIM, sU, tid);
    __syncthreads();  // drains vmcnt (async LDS writes complete)
#pragma unroll
    for (int kc = 0; kc < 8; kc += 2) {  // 4 K-steps of 32
      v4i a0 = frag_ld(sA, rA,      kc, half);
      v4i a1 = frag_ld(sA, rA + 32, kc, half);
      v4i g0 = frag_ld(sG, rB,      kc, half);
      v4i g1 = frag_ld(sG, rB + 32, kc, half);
      v4i u0 = frag_ld(sU, rB,      kc, half);
      v4i u1 = frag_ld(sU, rB + 32, kc, half);
      accG[0][0] = MFMA_I8(a0, g0, accG[0][0]);
      accG[0][1] = MFMA_I8(a0, g1, accG[0][1]);
      accG[1][0] = MFMA_I8(a1, g0, accG[1][0]);
      accG[1][1] = MFMA_I8(a1, g1, accG[1][1]);
      accU[0][0] = MFMA_I8(a0, u0, accU[0][0]);
      accU[0][1] = MFMA_I8(a0, u1, accU[0][1]);
      accU[1][0] = MFMA_I8(a1, u0, accU[1][0]);
      accU[1][1] = MFMA_I8(a1, u1, accU[1][1]);
    }
    __syncthreads();  // protect LDS before next stage
  }

  const float ga = gate_a[0];
  const float ua = up_a[0];
  const float inv_ds = 1.0f / down_scale[0];

#pragma unroll
  for (int tm = 0; tm < 2; ++tm) {
#pragma unroll
    for (int tn = 0; tn < 2; ++tn) {
      const int n = n0 + wn * 64 + tn * 32 + ln31;
      const float gb = gate_b[n];
      const float ub = up_b[n];
#pragma unroll
      for (int r = 0; r < 16; ++r) {
        // C/D layout (verified m74/m101): col=lane&31, row=(r&3)+8*(r>>2)+4*(lane>>5)
        const int row_l = (r & 3) + 8 * (r >> 2) + 4 * half;
        const int m = m0 + wm * 64 + tm * 32 + row_l;
        const float g = (float)accG[tm][tn][r] * ga + gb;
        const float u = (float)accU[tm][tn][r] * ua + ub;
        const float sg = g / (1.0f + __expf(-g));  // SiLU
        const float inter = sg * u;
        float qf = rintf(inter * inv_ds);          // round-half-even == jnp.round
        qf = fminf(127.0f, fmaxf(-128.0f, qf));
        Q[(size_t)m * IDIM + n] = (int8_t)qf;
      }
    }
  }
}

__global__ __launch_bounds__(256, 2) void k_down(
    const int8_t* __restrict__ Q,
    const int8_t* __restrict__ Wd,
    const float* __restrict__ down_a, const float* __restrict__ down_b,
    float* __restrict__ Out) {
  __shared__ __align__(16) int8_t sA[BM * BK];
  __shared__ __align__(16) int8_t sB[BN * BK];

  const int tid  = threadIdx.x;
  const int lane = tid & 63;
  const int wave = tid >> 6;
  const int wm   = wave >> 1;
  const int wn   = wave & 1;
  const int half = lane >> 5;
  const int ln31 = lane & 31;

  const int m0 = blockIdx.x * BM;
  const int n0 = blockIdx.y * BN;

  const int8_t* Ab = Q  + (size_t)m0 * IDIM;
  const int8_t* Bb = Wd + (size_t)n0 * IDIM;

  v16i acc[2][2];
#pragma unroll
  for (int i = 0; i < 2; ++i)
#pragma unroll
    for (int j = 0; j < 2; ++j)
#pragma unroll
      for (int e = 0; e < 16; ++e) acc[i][j][e] = 0;

  const int rA = wm * 64 + ln31;
  const int rB = wn * 64 + ln31;

  for (int k0 = 0; k0 < IDIM; k0 += BK) {  // 86 iterations
    async_stage_16kb(Ab + k0, IDIM, sA, tid);
    async_stage_16kb(Bb + k0, IDIM, sB, tid);
    __syncthreads();
#pragma unroll
    for (int kc = 0; kc < 8; kc += 2) {
      v4i a0 = frag_ld(sA, rA,      kc, half);
      v4i a1 = frag_ld(sA, rA + 32, kc, half);
      v4i b0 = frag_ld(sB, rB,      kc, half);
      v4i b1 = frag_ld(sB, rB + 32, kc, half);
      acc[0][0] = MFMA_I8(a0, b0, acc[0][0]);
      acc[0][1] = MFMA_I8(a0, b1, acc[0][1]);
      acc[1][0] = MFMA_I8(a1, b0, acc[1][0]);
      acc[1][1] = MFMA_I8(a1, b1, acc[1][1]);
    }
    __syncthreads();
  }

  const float da = down_a[0];
#pragma unroll
  for (int tm = 0; tm < 2; ++tm) {
#pragma unroll
    for (int tn = 0; tn < 2; ++tn) {
      const int n = n0 + wn * 64 + tn * 32 + ln31;
      const float db = down_b[n];
#pragma unroll
      for (int r = 0; r < 16; ++r) {
        const int row_l = (r & 3) + 8 * (r >> 2) + 4 * half;
        const int m = m0 + wm * 64 + tm * 32 + row_l;
        Out[(size_t)m * HDIM + n] = (float)acc[tm][tn][r] * da + db;
      }
    }
  }
}

extern "C" void kernel_launch(void* const* d_in, const int* in_sizes, int n_in,
                              void* d_out, int out_size, void* d_ws, size_t ws_size,
                              hipStream_t stream) {
  const int* X32        = (const int*)d_in[0];   // int8 values stored as int32
  const int* Wg32       = (const int*)d_in[1];
  const int* Wu32       = (const int*)d_in[2];
  const int* Wd32       = (const int*)d_in[3];
  const float* gate_a   = (const float*)d_in[4];
  const float* gate_b   = (const float*)d_in[5];
  const float* up_a     = (const float*)d_in[6];
  const float* up_b     = (const float*)d_in[7];
  const float* down_a   = (const float*)d_in[8];
  const float* down_b   = (const float*)d_in[9];
  const float* down_scale = (const float*)d_in[10];
  float* Out = (float*)d_out;

  const size_t nX = (size_t)M_TOT * HDIM;        // 16,777,216
  const size_t nW = (size_t)IDIM * HDIM;         // 45,088,768 (gate/up/down all same count)

  // Workspace layout (bytes): Q | Xp | Wgp | Wup | Wdp  => ~197 MB total
  int8_t* Q   = (int8_t*)d_ws;                   // 45,088,768
  int8_t* Xp  = Q   + nW;                        // 16,777,216
  int8_t* Wgp = Xp  + nX;                        // 45,088,768
  int8_t* Wup = Wgp + nW;                        // 45,088,768
  int8_t* Wdp = Wup + nW;                        // 45,088,768

  // Pack int32 -> int8 (16 elements/thread)
  {
    int n16 = (int)(nX / 16);
    k_pack<<<(n16 + 255) / 256, 256, 0, stream>>>(X32, Xp, n16);
    n16 = (int)(nW / 16);
    k_pack<<<(n16 + 255) / 256, 256, 0, stream>>>(Wg32, Wgp, n16);
    k_pack<<<(n16 + 255) / 256, 256, 0, stream>>>(Wu32, Wup, n16);
    k_pack<<<(n16 + 255) / 256, 256, 0, stream>>>(Wd32, Wdp, n16);
  }

  dim3 g1(M_TOT / BM, IDIM / BN);  // 32 x 86
  k_gateup<<<g1, dim3(256), 0, stream>>>(Xp, Wgp, Wup, gate_a, gate_b, up_a, up_b,
                                         down_scale, Q);
  dim3 g2(M_TOT / BM, HDIM / BN);  // 32 x 32
  k_down<<<g2, dim3(256), 0, stream>>>(Q, Wdp, down_a, down_b, Out);
}

// Round 3
// 1122.885 us; speedup vs baseline: 1.0075x; 1.0075x over previous
//
#include <hip/hip_runtime.h>
#include <cstdint>

// LlamaSmoothquantMLP on MI355X (gfx950).
// Harness materializes integer inputs as int32 -> pack to int8 in d_ws first.
//
// Pass 0 (k_pack_all): one dispatch packs X, Wg, Wu, Wd int32->int8.
// Kernel 1 (k_gateup): fused gate+up int8 GEMM + dequant + SiLU + mul +
//                      requant -> int8 Q.   [38% of i8 MFMA ceiling]
// Kernel 2 (k_down):   down int8 GEMM + dequant + bias -> fp32.
//                      Wave tile 128Mx64N (ratio 1.33) to match gateup's
//                      plateau efficiency.
//
// GEMMs: A [M,K] row-major, B [N,K] row-major (K-contiguous both sides).
// MFMA: v_mfma_i32_32x32x32_i8. Staging: global_load_lds width=16 with XOR-8
// chunk swizzle on the *global* source address (LDS side of global_load_lds
// is fixed uniform-base + lane*16), balancing banks for ds_read_b128.

typedef int v4i  __attribute__((ext_vector_type(4)));
typedef int v16i __attribute__((ext_vector_type(16)));

typedef const void __attribute__((address_space(1)))* gas_ptr;
typedef void __attribute__((address_space(3)))* las_ptr;

static constexpr int M_TOT = 4096;   // B*S
static constexpr int HDIM  = 4096;
static constexpr int IDIM  = 11008;

#define BM 128
#define BN 128
#define BK 128

// ---------------- pack int32 -> int8, all four tensors in one dispatch ------
__device__ __forceinline__ void pack16(const int* __restrict__ src,
                                       int8_t* __restrict__ dst, int t) {
  const int4* s = (const int4*)(src) + t * 4;
  int4 v0 = s[0], v1 = s[1], v2 = s[2], v3 = s[3];
  int p0 = (v0.x & 0xff) | ((v0.y & 0xff) << 8) | ((v0.z & 0xff) << 16) | (v0.w << 24);
  int p1 = (v1.x & 0xff) | ((v1.y & 0xff) << 8) | ((v1.z & 0xff) << 16) | (v1.w << 24);
  int p2 = (v2.x & 0xff) | ((v2.y & 0xff) << 8) | ((v2.z & 0xff) << 16) | (v2.w << 24);
  int p3 = (v3.x & 0xff) | ((v3.y & 0xff) << 8) | ((v3.z & 0xff) << 16) | (v3.w << 24);
  ((int4*)dst)[t] = make_int4(p0, p1, p2, p3);
}

static constexpr int CX = (M_TOT * HDIM) / 16;            // 1,048,576
static constexpr int CW = (IDIM * HDIM) / 16;             // 2,818,048
static constexpr int CTOT = CX + 3 * CW;                  // 9,502,720

__global__ __launch_bounds__(256) void k_pack_all(
    const int* __restrict__ X32, const int* __restrict__ Wg32,
    const int* __restrict__ Wu32, const int* __restrict__ Wd32,
    int8_t* __restrict__ Xp, int8_t* __restrict__ Wgp,
    int8_t* __restrict__ Wup, int8_t* __restrict__ Wdp) {
  int t = blockIdx.x * blockDim.x + threadIdx.x;
  if (t >= CTOT) return;
  if (t < CX)               { pack16(X32,  Xp,  t); return; }
  t -= CX;
  if (t < CW)               { pack16(Wg32, Wgp, t); return; }
  t -= CW;
  if (t < CW)               { pack16(Wu32, Wup, t); return; }
  t -= CW;
  pack16(Wd32, Wdp, t);
}

// ---------------- staging ----------------
// Stage one 128-row x 128-byte tile (16 KiB) global->LDS asynchronously.
// 256 threads x 4 iters x 16B. LDS slot s of row r holds global chunk s^(r&7).
__device__ __forceinline__ void async_stage_16kb(const int8_t* __restrict__ gbase,
                                                 int ld, int8_t* lds, int tid) {
#pragma unroll
  for (int it = 0; it < 4; ++it) {
    const int chunk = it * 256 + tid;      // 0..1023
    const int row   = chunk >> 3;          // 0..127
    const int slot  = chunk & 7;           // 0..7
    const int gch   = slot ^ (row & 7);    // swizzled source chunk
    const int8_t* g = gbase + row * ld + gch * 16;
    int8_t* l = lds + chunk * 16;
    __builtin_amdgcn_global_load_lds((gas_ptr)g, (las_ptr)l, 16, 0, 0);
  }
}

// Read a 16-byte fragment for row `row` (tile-local), K-chunk base `kc`
// (0,2,4,6), lane-half `half`. Undo the XOR-8 swizzle.
__device__ __forceinline__ v4i frag_ld(const int8_t* lds, int row, int kc, int half) {
  const int ch  = kc + half;
  const int sch = ch ^ (row & 7);
  return *(const v4i*)(lds + row * 128 + sch * 16);
}

#define MFMA_I8(a, b, c) __builtin_amdgcn_mfma_i32_32x32x32_i8((a), (b), (c), 0, 0, 0)

// ---------------- gate+up fused GEMM ----------------
__global__ __launch_bounds__(256, 2) void k_gateup(
    const int8_t* __restrict__ X,
    const int8_t* __restrict__ Wg,
    const int8_t* __restrict__ Wu,
    const float* __restrict__ gate_a, const float* __restrict__ gate_b,
    const float* __restrict__ up_a,   const float* __restrict__ up_b,
    const float* __restrict__ down_scale,
    int8_t* __restrict__ Q) {
  __shared__ __align__(16) int8_t sA[BM * BK];
  __shared__ __align__(16) int8_t sG[BN * BK];
  __shared__ __align__(16) int8_t sU[BN * BK];

  const int tid  = threadIdx.x;
  const int lane = tid & 63;
  const int wave = tid >> 6;
  const int wm   = wave >> 1;
  const int wn   = wave & 1;
  const int half = lane >> 5;
  const int ln31 = lane & 31;

  const int m0 = blockIdx.x * BM;
  const int n0 = blockIdx.y * BN;

  const int8_t* Ab = X  + (size_t)m0 * HDIM;
  const int8_t* Gb = Wg + (size_t)n0 * HDIM;
  const int8_t* Ub = Wu + (size_t)n0 * HDIM;

  v16i accG[2][2], accU[2][2];
#pragma unroll
  for (int i = 0; i < 2; ++i)
#pragma unroll
    for (int j = 0; j < 2; ++j)
#pragma unroll
      for (int e = 0; e < 16; ++e) { accG[i][j][e] = 0; accU[i][j][e] = 0; }

  const int rA = wm * 64 + ln31;
  const int rB = wn * 64 + ln31;

  for (int k0 = 0; k0 < HDIM; k0 += BK) {
    async_stage_16kb(Ab + k0, HDIM, sA, tid);
    async_stage_16kb(Gb + k0, HDIM, sG, tid);
    async_stage_16kb(Ub + k0, HDIM, sU, tid);
    __syncthreads();
#pragma unroll
    for (int kc = 0; kc < 8; kc += 2) {
      v4i a0 = frag_ld(sA, rA,      kc, half);
      v4i a1 = frag_ld(sA, rA + 32, kc, half);
      v4i g0 = frag_ld(sG, rB,      kc, half);
      v4i g1 = frag_ld(sG, rB + 32, kc, half);
      v4i u0 = frag_ld(sU, rB,      kc, half);
      v4i u1 = frag_ld(sU, rB + 32, kc, half);
      accG[0][0] = MFMA_I8(a0, g0, accG[0][0]);
      accG[0][1] = MFMA_I8(a0, g1, accG[0][1]);
      accG[1][0] = MFMA_I8(a1, g0, accG[1][0]);
      accG[1][1] = MFMA_I8(a1, g1, accG[1][1]);
      accU[0][0] = MFMA_I8(a0, u0, accU[0][0]);
      accU[0][1] = MFMA_I8(a0, u1, accU[0][1]);
      accU[1][0] = MFMA_I8(a1, u0, accU[1][0]);
      accU[1][1] = MFMA_I8(a1, u1, accU[1][1]);
    }
    __syncthreads();
  }

  const float ga = gate_a[0];
  const float ua = up_a[0];
  const float inv_ds = 1.0f / down_scale[0];

#pragma unroll
  for (int tm = 0; tm < 2; ++tm) {
#pragma unroll
    for (int tn = 0; tn < 2; ++tn) {
      const int n = n0 + wn * 64 + tn * 32 + ln31;
      const float gb = gate_b[n];
      const float ub = up_b[n];
#pragma unroll
      for (int r = 0; r < 16; ++r) {
        // C/D layout (m74/m101): col=lane&31, row=(r&3)+8*(r>>2)+4*(lane>>5)
        const int row_l = (r & 3) + 8 * (r >> 2) + 4 * half;
        const int m = m0 + wm * 64 + tm * 32 + row_l;
        const float g = (float)accG[tm][tn][r] * ga + gb;
        const float u = (float)accU[tm][tn][r] * ua + ub;
        const float sg = g / (1.0f + __expf(-g));
        const float inter = sg * u;
        float qf = rintf(inter * inv_ds);
        qf = fminf(127.0f, fmaxf(-128.0f, qf));
        Q[(size_t)m * IDIM + n] = (int8_t)qf;
      }
    }
  }
}

// ---------------- down GEMM: block 256Mx128N, wave 128Mx64N ----------------
__global__ __launch_bounds__(256, 2) void k_down(
    const int8_t* __restrict__ Q,
    const int8_t* __restrict__ Wd,
    const float* __restrict__ down_a, const float* __restrict__ down_b,
    float* __restrict__ Out) {
  __shared__ __align__(16) int8_t sA[256 * BK];   // 32 KB
  __shared__ __align__(16) int8_t sB[128 * BK];   // 16 KB

  const int tid  = threadIdx.x;
  const int lane = tid & 63;
  const int wave = tid >> 6;
  const int wm   = wave >> 1;   // M half (0/1), 128 rows each
  const int wn   = wave & 1;    // N half (0/1), 64 cols each
  const int half = lane >> 5;
  const int ln31 = lane & 31;

  const int m0 = blockIdx.x * 256;
  const int n0 = blockIdx.y * 128;

  const int8_t* Ab = Q  + (size_t)m0 * IDIM;
  const int8_t* Bb = Wd + (size_t)n0 * IDIM;

  v16i acc[4][2];
#pragma unroll
  for (int i = 0; i < 4; ++i)
#pragma unroll
    for (int j = 0; j < 2; ++j)
#pragma unroll
      for (int e = 0; e < 16; ++e) acc[i][j][e] = 0;

  const int rA = wm * 128 + ln31;   // A tile rows 0..255
  const int rB = wn * 64 + ln31;    // B tile rows 0..127

  for (int k0 = 0; k0 < IDIM; k0 += BK) {  // 86 iterations
    async_stage_16kb(Ab + k0, IDIM, sA, tid);
    async_stage_16kb(Ab + (size_t)128 * IDIM + k0, IDIM, sA + 128 * BK, tid);
    async_stage_16kb(Bb + k0, IDIM, sB, tid);
    __syncthreads();
#pragma unroll
    for (int kc = 0; kc < 8; kc += 2) {
      v4i a0 = frag_ld(sA, rA,      kc, half);
      v4i a1 = frag_ld(sA, rA + 32, kc, half);
      v4i a2 = frag_ld(sA, rA + 64, kc, half);
      v4i a3 = frag_ld(sA, rA + 96, kc, half);
      v4i b0 = frag_ld(sB, rB,      kc, half);
      v4i b1 = frag_ld(sB, rB + 32, kc, half);
      acc[0][0] = MFMA_I8(a0, b0, acc[0][0]);
      acc[0][1] = MFMA_I8(a0, b1, acc[0][1]);
      acc[1][0] = MFMA_I8(a1, b0, acc[1][0]);
      acc[1][1] = MFMA_I8(a1, b1, acc[1][1]);
      acc[2][0] = MFMA_I8(a2, b0, acc[2][0]);
      acc[2][1] = MFMA_I8(a2, b1, acc[2][1]);
      acc[3][0] = MFMA_I8(a3, b0, acc[3][0]);
      acc[3][1] = MFMA_I8(a3, b1, acc[3][1]);
    }
    __syncthreads();
  }

  const float da = down_a[0];
#pragma unroll
  for (int tm = 0; tm < 4; ++tm) {
#pragma unroll
    for (int tn = 0; tn < 2; ++tn) {
      const int n = n0 + wn * 64 + tn * 32 + ln31;
      const float db = down_b[n];
#pragma unroll
      for (int r = 0; r < 16; ++r) {
        const int row_l = (r & 3) + 8 * (r >> 2) + 4 * half;
        const int m = m0 + wm * 128 + tm * 32 + row_l;
        Out[(size_t)m * HDIM + n] = (float)acc[tm][tn][r] * da + db;
      }
    }
  }
}

extern "C" void kernel_launch(void* const* d_in, const int* in_sizes, int n_in,
                              void* d_out, int out_size, void* d_ws, size_t ws_size,
                              hipStream_t stream) {
  const int* X32        = (const int*)d_in[0];
  const int* Wg32       = (const int*)d_in[1];
  const int* Wu32       = (const int*)d_in[2];
  const int* Wd32       = (const int*)d_in[3];
  const float* gate_a   = (const float*)d_in[4];
  const float* gate_b   = (const float*)d_in[5];
  const float* up_a     = (const float*)d_in[6];
  const float* up_b     = (const float*)d_in[7];
  const float* down_a   = (const float*)d_in[8];
  const float* down_b   = (const float*)d_in[9];
  const float* down_scale = (const float*)d_in[10];
  float* Out = (float*)d_out;

  const size_t nX = (size_t)M_TOT * HDIM;
  const size_t nW = (size_t)IDIM * HDIM;

  // Workspace: Q | Xp | Wgp | Wup | Wdp  (~197 MB)
  int8_t* Q   = (int8_t*)d_ws;
  int8_t* Xp  = Q   + nW;
  int8_t* Wgp = Xp  + nX;
  int8_t* Wup = Wgp + nW;
  int8_t* Wdp = Wup + nW;

  k_pack_all<<<(CTOT + 255) / 256, 256, 0, stream>>>(X32, Wg32, Wu32, Wd32,
                                                     Xp, Wgp, Wup, Wdp);

  dim3 g1(M_TOT / BM, IDIM / BN);  // 32 x 86
  k_gateup<<<g1, dim3(256), 0, stream>>>(Xp, Wgp, Wup, gate_a, gate_b, up_a, up_b,
                                         down_scale, Q);
  dim3 g2(M_TOT / 256, HDIM / 128);  // 16 x 32
  k_down<<<g2, dim3(256), 0, stream>>>(Q, Wdp, down_a, down_b, Out);
}